// Round 7
// baseline (323.905 us; speedup 1.0000x reference)
//
#include <hip/hip_runtime.h>
#include <hip/hip_fp16.h>

#define B_  8
#define C_  256
#define H_  64
#define W_  64
#define G_  4
#define CG_ 64
#define K_  9
#define HW_ (H_ * W_)  // 4096

#define WIN_H 16
#define WIN_W 28
#define NLINES (WIN_H * WIN_W)   // 448 lines x 128B = 57344 B

// ---------------------------------------------------------------------------
// Kernel 1: NCHW fp32 -> group-major NHWC fp16  [B,C,HW] -> [B,G,HW,CG]
// ---------------------------------------------------------------------------
__global__ __launch_bounds__(256) void to_ghwc_f16(const float* __restrict__ in,
                                                   __half* __restrict__ out) {
  __shared__ unsigned int tile[32][65];  // [channel-pair][pixel]
  const int b  = blockIdx.z;
  const int p0 = blockIdx.x * 64;
  const int g  = blockIdx.y;
  const int tid = threadIdx.x;
  const float* src = in + (size_t)b * C_ * HW_ + (size_t)g * CG_ * HW_;
  __half* dst = out + ((size_t)(b * G_ + g) * HW_) * CG_;

  const int px  = tid & 63;
  const int cp0 = tid >> 6;
#pragma unroll
  for (int i = 0; i < 8; ++i) {
    const int cp = cp0 + i * 4;
    const int c  = cp * 2;
    const float v0 = src[(size_t)c * HW_ + p0 + px];
    const float v1 = src[(size_t)(c + 1) * HW_ + p0 + px];
    const unsigned int lo = (unsigned int)__half_as_ushort(__float2half(v0));
    const unsigned int hi = (unsigned int)__half_as_ushort(__float2half(v1));
    tile[cp][px] = lo | (hi << 16);
  }
  __syncthreads();

  const int cpair = tid & 31;
  const int pr0   = tid >> 5;
#pragma unroll
  for (int i = 0; i < 8; ++i) {
    const int p = pr0 + i * 8;
    *(unsigned int*)(dst + (size_t)(p0 + p) * CG_ + 2 * cpair) = tile[cpair][p];
  }
}

// ---------------------------------------------------------------------------
// Kernel 2: deformable sampling, LDS-staged window.
//   Block = (b,g) x 4x16 output tile. Stage the 16x28-pixel window
//   (57.3 KB, covers |offset|<=4; ~1.3e-4 of entries fall outside and use a
//   sign-encoded global fallback) into LDS, then all bilinear corner gathers
//   are ds_read_b128. Chunks XOR-rotated by (line&7) on write AND read to
//   spread pixel-lines across banks. XCD swizzle keeps the (b,g) slab
//   L2-resident for the staging reads.
// ---------------------------------------------------------------------------
union DeformSM {
  struct {
    char   stage[NLINES * 128];  // 57344
    int4   o[576];               // 9216
    float4 w[576];               // 9216
  } s;                            // 75776 B -> 2 blocks/CU
  float ot[64][65];               // overlays stage after gathers complete
};

__global__ __launch_bounds__(256, 2) void deform_g16s(const __half* __restrict__ x,
                                                      const float* __restrict__ off,
                                                      const float* __restrict__ msk,
                                                      float* __restrict__ out) {
  __shared__ DeformSM sm;

  // XCD-aware swizzle: grid 2048 % 8 == 0; XCD i owns contiguous bg slabs.
  const int orig = blockIdx.x;                    // 0..2047
  const int wgid = (orig & 7) * 256 + (orig >> 3);
  const int tile = wgid & 63;                     // 64 tiles per (b,g)
  const int bg   = wgid >> 6;
  const int ho0  = (tile >> 2) * 4;               // 16 row-tiles
  const int wo0  = (tile & 3) * 16;               // 4 col-tiles
  const int b    = bg >> 2;
  const int g    = bg & 3;
  const int tid  = threadIdx.x;

  const int wy0 = min(max(ho0 - 5, 0), H_ - WIN_H);   // 0..48
  const int wx0 = min(max(wo0 - 5, 0), W_ - WIN_W);   // 0..36
  const char* slab = (const char*)x + (size_t)(b * G_ + g) * (HW_ * CG_ * 2);

  // ---- stage the window: 448 lines x 8 chunks of 16B, chunk ^= (line&7) ----
#pragma unroll
  for (int i = 0; i < 14; ++i) {
    const int t = tid + i * 256;     // 0..3583
    const int L = t >> 3, c = t & 7;
    const int ry = L / WIN_W, rx = L - ry * WIN_W;
    const float4 v = *(const float4*)(slab + ((((wy0 + ry) * W_ + wx0 + rx) << 7) + (c << 4)));
    *(float4*)(sm.s.stage + (L << 7) + ((c ^ (L & 7)) << 4)) = v;
  }

  // ---- params for 64 tile pixels x 9 taps ----
  for (int e = tid; e < 576; e += 256) {
    const int px  = e & 63;
    const int k   = e >> 6;
    const int row = px >> 4, col = px & 15;
    const int ho  = ho0 + row, wo = wo0 + col;
    const int ky = k / 3, kx = k - ky * 3;
    const int och = (g * K_ + k) * 2;
    const size_t ob = ((size_t)(b * (2 * G_ * K_) + och) * HW_) + ho * W_ + wo;
    const float dy = off[ob];
    const float dx = off[ob + HW_];
    const float m  = msk[((size_t)(b * (G_ * K_) + g * K_ + k) * HW_) + ho * W_ + wo];

    const float py  = (float)(ho - 1 + ky) + dy;
    const float pxx = (float)(wo - 1 + kx) + dx;
    const float fy = floorf(py), fx = floorf(pxx);
    const int y0 = (int)fy, x0 = (int)fx;
    const int y1 = y0 + 1,  x1 = x0 + 1;
    const float ly = py - fy, lx = pxx - fx;

    const bool vy0 = ((unsigned)y0 < (unsigned)H_), vy1 = ((unsigned)y1 < (unsigned)H_);
    const bool vx0 = ((unsigned)x0 < (unsigned)W_), vx1 = ((unsigned)x1 < (unsigned)W_);
    const float wy0f = (1.f - ly) * m, wy1f = ly * m;

    float4 w;
    w.x = (vy0 && vx0) ? wy0f * (1.f - lx) : 0.f;
    w.y = (vy0 && vx1) ? wy0f * lx         : 0.f;
    w.z = (vy1 && vx0) ? wy1f * (1.f - lx) : 0.f;
    w.w = (vy1 && vx1) ? wy1f * lx         : 0.f;

    const int y0c = min(max(y0, 0), H_ - 1), y1c = min(max(y1, 0), H_ - 1);
    const int x0c = min(max(x0, 0), W_ - 1), x1c = min(max(x1, 0), W_ - 1);

    const int ry0 = y0c - wy0, ry1 = y1c - wy0;
    const int rx0 = x0c - wx0, rx1 = x1c - wx0;
    const bool inw = ((unsigned)ry0 < WIN_H) & ((unsigned)ry1 < WIN_H) &
                     ((unsigned)rx0 < WIN_W) & ((unsigned)rx1 < WIN_W);

    int4 o;
    if (inw) {  // LDS byte offsets (>= 0)
      o.x = (ry0 * WIN_W + rx0) << 7;
      o.y = (ry0 * WIN_W + rx1) << 7;
      o.z = (ry1 * WIN_W + rx0) << 7;
      o.w = (ry1 * WIN_W + rx1) << 7;
    } else {    // global byte offsets, sign-encoded (~v < 0)
      o.x = ~((y0c * W_ + x0c) << 7);
      o.y = ~((y0c * W_ + x1c) << 7);
      o.z = ~((y1c * W_ + x0c) << 7);
      o.w = ~((y1c * W_ + x1c) << 7);
    }
    sm.s.o[e] = o;
    sm.s.w[e] = w;
  }
  __syncthreads();

  // ---- gather + accumulate: 2 tile-pixels x 8 channels per thread ----
  const int ci16 = (tid & 7) * 16;   // byte offset of channel octet
  const int wi   = tid >> 3;         // slot 0..31

  float a0[8] = {0.f, 0.f, 0.f, 0.f, 0.f, 0.f, 0.f, 0.f};
  float a1[8] = {0.f, 0.f, 0.f, 0.f, 0.f, 0.f, 0.f, 0.f};

#pragma unroll
  for (int k = 0; k < 9; ++k) {
    const int eA = k * 64 + wi;
    const int4   oA = sm.s.o[eA];
    const float4 wA = sm.s.w[eA];
    const int4   oB = sm.s.o[eA + 32];
    const float4 wB = sm.s.w[eA + 32];

    float4 rA0, rA1, rA2, rA3, rB0, rB1, rB2, rB3;
    if (oA.x >= 0) {
      rA0 = *(const float4*)(sm.s.stage + oA.x + (ci16 ^ ((oA.x >> 3) & 0x70)));
      rA1 = *(const float4*)(sm.s.stage + oA.y + (ci16 ^ ((oA.y >> 3) & 0x70)));
      rA2 = *(const float4*)(sm.s.stage + oA.z + (ci16 ^ ((oA.z >> 3) & 0x70)));
      rA3 = *(const float4*)(sm.s.stage + oA.w + (ci16 ^ ((oA.w >> 3) & 0x70)));
    } else {
      rA0 = *(const float4*)(slab + (~oA.x + ci16));
      rA1 = *(const float4*)(slab + (~oA.y + ci16));
      rA2 = *(const float4*)(slab + (~oA.z + ci16));
      rA3 = *(const float4*)(slab + (~oA.w + ci16));
    }
    if (oB.x >= 0) {
      rB0 = *(const float4*)(sm.s.stage + oB.x + (ci16 ^ ((oB.x >> 3) & 0x70)));
      rB1 = *(const float4*)(sm.s.stage + oB.y + (ci16 ^ ((oB.y >> 3) & 0x70)));
      rB2 = *(const float4*)(sm.s.stage + oB.z + (ci16 ^ ((oB.z >> 3) & 0x70)));
      rB3 = *(const float4*)(sm.s.stage + oB.w + (ci16 ^ ((oB.w >> 3) & 0x70)));
    } else {
      rB0 = *(const float4*)(slab + (~oB.x + ci16));
      rB1 = *(const float4*)(slab + (~oB.y + ci16));
      rB2 = *(const float4*)(slab + (~oB.z + ci16));
      rB3 = *(const float4*)(slab + (~oB.w + ci16));
    }

    const __half* hA0 = (const __half*)&rA0;
    const __half* hA1 = (const __half*)&rA1;
    const __half* hA2 = (const __half*)&rA2;
    const __half* hA3 = (const __half*)&rA3;
    const __half* hB0 = (const __half*)&rB0;
    const __half* hB1 = (const __half*)&rB1;
    const __half* hB2 = (const __half*)&rB2;
    const __half* hB3 = (const __half*)&rB3;
#pragma unroll
    for (int j = 0; j < 8; ++j) {
      float s0 = a0[j];
      s0 = fmaf(wA.x, __half2float(hA0[j]), s0);
      s0 = fmaf(wA.y, __half2float(hA1[j]), s0);
      s0 = fmaf(wA.z, __half2float(hA2[j]), s0);
      s0 = fmaf(wA.w, __half2float(hA3[j]), s0);
      a0[j] = s0;
      float s1 = a1[j];
      s1 = fmaf(wB.x, __half2float(hB0[j]), s1);
      s1 = fmaf(wB.y, __half2float(hB1[j]), s1);
      s1 = fmaf(wB.z, __half2float(hB2[j]), s1);
      s1 = fmaf(wB.w, __half2float(hB3[j]), s1);
      a1[j] = s1;
    }
  }

  __syncthreads();  // stage + params dead; reuse LDS as output tile
  {
    const int ci = tid & 7;
#pragma unroll
    for (int j = 0; j < 8; ++j) {
      sm.ot[ci * 8 + j][wi]      = a0[j];
      sm.ot[ci * 8 + j][wi + 32] = a1[j];
    }
  }
  __syncthreads();

  // ---- stores: wave covers 64 px of one channel = 4 x 64B segments ----
  float* obp = out + ((size_t)(b * C_ + g * CG_)) * HW_;
#pragma unroll
  for (int q = 0; q < 16; ++q) {
    const int flat = q * 256 + tid;
    const int c  = flat >> 6;          // uniform across a wave
    const int px = flat & 63;
    const int ho = ho0 + (px >> 4), wo = wo0 + (px & 15);
    obp[(size_t)c * HW_ + ho * W_ + wo] = sm.ot[c][px];
  }
}

// ---------------------------------------------------------------------------
// Fallback (no workspace): fp32 NCHW gathers, 4 ch/thread.
// ---------------------------------------------------------------------------
__global__ __launch_bounds__(256) void deform_f32_nchw(const float* __restrict__ x,
                                                       const float* __restrict__ off,
                                                       const float* __restrict__ msk,
                                                       float* __restrict__ out) {
  __shared__ int4   s_o[144];
  __shared__ float4 s_w[144];
  const int woq = blockIdx.x;
  const int ho  = blockIdx.y;
  const int b   = blockIdx.z >> 2;
  const int g   = blockIdx.z & 3;
  const int tid = threadIdx.x;

  if (tid < 144) {
    const int wi = tid / 9, k = tid - wi * 9;
    const int wo = woq * 16 + wi;
    const int ky = k / 3, kx = k - ky * 3;
    const int och = (g * K_ + k) * 2;
    const size_t ob = ((size_t)(b * (2 * G_ * K_) + och) * H_ + ho) * W_ + wo;
    const float dy = off[ob];
    const float dx = off[ob + HW_];
    const float m  = msk[((size_t)(b * (G_ * K_) + g * K_ + k) * H_ + ho) * W_ + wo];
    const float py = (float)(ho - 1 + ky) + dy;
    const float px = (float)(wo - 1 + kx) + dx;
    const float fy = floorf(py), fx = floorf(px);
    const int y0 = (int)fy, x0 = (int)fx;
    const int y1 = y0 + 1,  x1 = x0 + 1;
    const float ly = py - fy, lx = px - fx;
    const bool vy0 = ((unsigned)y0 < (unsigned)H_), vy1 = ((unsigned)y1 < (unsigned)H_);
    const bool vx0 = ((unsigned)x0 < (unsigned)W_), vx1 = ((unsigned)x1 < (unsigned)W_);
    const float wy0 = (1.f - ly) * m, wy1 = ly * m;
    float4 w;
    w.x = (vy0 && vx0) ? wy0 * (1.f - lx) : 0.f;
    w.y = (vy0 && vx1) ? wy0 * lx         : 0.f;
    w.z = (vy1 && vx0) ? wy1 * (1.f - lx) : 0.f;
    w.w = (vy1 && vx1) ? wy1 * lx         : 0.f;
    const int y0c = min(max(y0, 0), H_ - 1), y1c = min(max(y1, 0), H_ - 1);
    const int x0c = min(max(x0, 0), W_ - 1), x1c = min(max(x1, 0), W_ - 1);
    s_o[tid] = make_int4(y0c * W_ + x0c, y0c * W_ + x1c, y1c * W_ + x0c, y1c * W_ + x1c);
    s_w[tid] = w;
  }
  __syncthreads();

  const int ci = tid & 15, wi = tid >> 4;
  const float* xb = x + (size_t)(b * C_ + g * CG_ + ci * 4) * HW_;
  float a0 = 0.f, a1 = 0.f, a2 = 0.f, a3 = 0.f;
#pragma unroll
  for (int k = 0; k < 9; ++k) {
    const int e = wi * 9 + k;
    const int4   o = s_o[e];
    const float4 w = s_w[e];
    a0 += w.x * xb[o.x] + w.y * xb[o.y] + w.z * xb[o.z] + w.w * xb[o.w];
    const float* x1p = xb + HW_;
    a1 += w.x * x1p[o.x] + w.y * x1p[o.y] + w.z * x1p[o.z] + w.w * x1p[o.w];
    const float* x2p = xb + 2 * HW_;
    a2 += w.x * x2p[o.x] + w.y * x2p[o.y] + w.z * x2p[o.z] + w.w * x2p[o.w];
    const float* x3p = xb + 3 * HW_;
    a3 += w.x * x3p[o.x] + w.y * x3p[o.y] + w.z * x3p[o.z] + w.w * x3p[o.w];
  }
  float* ob = out + ((size_t)(b * C_ + g * CG_ + ci * 4)) * HW_ + ho * W_ + woq * 16 + wi;
  ob[0] = a0; ob[HW_] = a1; ob[2 * HW_] = a2; ob[3 * HW_] = a3;
}

// ---------------------------------------------------------------------------
extern "C" void kernel_launch(void* const* d_in, const int* in_sizes, int n_in,
                              void* d_out, int out_size, void* d_ws, size_t ws_size,
                              hipStream_t stream) {
  const float* inp = (const float*)d_in[0];
  const float* off = (const float*)d_in[1];
  const float* msk = (const float*)d_in[2];
  float* out = (float*)d_out;

  const size_t need = (size_t)B_ * C_ * HW_ * sizeof(__half);  // 16.8 MB
  if (ws_size >= need) {
    __half* xt = (__half*)d_ws;
    to_ghwc_f16<<<dim3(HW_ / 64, G_, B_), 256, 0, stream>>>(inp, xt);
    deform_g16s<<<dim3(H_ * B_ * G_), 256, 0, stream>>>(xt, off, msk, out);
  } else {
    deform_f32_nchw<<<dim3(4, H_, B_ * G_), 256, 0, stream>>>(inp, off, msk, out);
  }
}

// Round 8
// 49.484 us; speedup vs baseline: 6.5457x; 6.5457x over previous
//
#include <hip/hip_runtime.h>
#include <hip/hip_fp16.h>

#define B_  8
#define C_  256
#define H_  64
#define W_  64
#define G_  4
#define CG_ 64
#define K_  9
#define HW_ (H_ * W_)  // 4096

#define TH_ 4
#define TW_ 16
#define WIN_H 14
#define WIN_W 26
#define NL_ (WIN_H * WIN_W)   // 364 lines x 128B = 46592 B

// ---------------------------------------------------------------------------
// Kernel 1: NCHW fp32 -> group-major NHWC fp16  [B,C,HW] -> [B,G,HW,CG]
// ---------------------------------------------------------------------------
__global__ __launch_bounds__(256) void to_ghwc_f16(const float* __restrict__ in,
                                                   __half* __restrict__ out) {
  __shared__ unsigned int tile[32][65];  // [channel-pair][pixel]
  const int b  = blockIdx.z;
  const int p0 = blockIdx.x * 64;
  const int g  = blockIdx.y;
  const int tid = threadIdx.x;
  const float* src = in + (size_t)b * C_ * HW_ + (size_t)g * CG_ * HW_;
  __half* dst = out + ((size_t)(b * G_ + g) * HW_) * CG_;

  const int px  = tid & 63;
  const int cp0 = tid >> 6;
#pragma unroll
  for (int i = 0; i < 8; ++i) {
    const int cp = cp0 + i * 4;
    const int c  = cp * 2;
    const float v0 = src[(size_t)c * HW_ + p0 + px];
    const float v1 = src[(size_t)(c + 1) * HW_ + p0 + px];
    const unsigned int lo = (unsigned int)__half_as_ushort(__float2half(v0));
    const unsigned int hi = (unsigned int)__half_as_ushort(__float2half(v1));
    tile[cp][px] = lo | (hi << 16);
  }
  __syncthreads();

  const int cpair = tid & 31;
  const int pr0   = tid >> 5;
#pragma unroll
  for (int i = 0; i < 8; ++i) {
    const int p = pr0 + i * 8;
    *(unsigned int*)(dst + (size_t)(p0 + p) * CG_ + 2 * cpair) = tile[cpair][p];
  }
}

// ---------------------------------------------------------------------------
// Kernel 2: LDS-staged deformable sampling.
//   Block = (b,g) x 4x16 tile. Stage the 14x26-pixel window (45.5 KB) into
//   LDS; all corner gathers become ds_read_b128. Out-of-window corners
//   (~0.15/block) go to a fallback list processed after the main loop via
//   LDS atomicAdd -> hot loop is branch-free. Chunk-XOR swizzle (write+read)
//   spreads lines across banks. XCD swizzle keeps the slab L2-resident.
// ---------------------------------------------------------------------------
struct DeformSM {
  union {
    char  stage[NL_ * 128];      // 46592
    float ot[64][65];            // 16640 — overlays stage after main loop
  } u;
  short4 l[576];                 // 4608  corner line indices
  float4 w[576];                 // 9216  masked bilinear weights
  int    l_px[64];               // fallback list
  int4   l_o[64];
  float4 l_w[64];
  int    ln;
};                               // 62724 B -> 2 blocks/CU

__global__ __launch_bounds__(256, 2) void deform_g16s(const __half* __restrict__ x,
                                                      const float* __restrict__ off,
                                                      const float* __restrict__ msk,
                                                      float* __restrict__ out) {
  __shared__ DeformSM sm;

  const int orig = blockIdx.x;                    // 0..2047
  const int wgid = (orig & 7) * 256 + (orig >> 3);
  const int tile = wgid & 63;
  const int bg   = wgid >> 6;
  const int ho0  = (tile >> 2) * TH_;             // 16 row-tiles
  const int wo0  = (tile & 3) * TW_;              // 4 col-tiles
  const int b    = bg >> 2;
  const int g    = bg & 3;
  const int tid  = threadIdx.x;

  const int wy0 = min(max(ho0 - 5, 0), H_ - WIN_H);  // rows [wy0, wy0+14)
  const int wx0 = min(max(wo0 - 5, 0), W_ - WIN_W);  // cols [wx0, wx0+26)
  const char* slab = (const char*)x + (size_t)(b * G_ + g) * (HW_ * CG_ * 2);

  if (tid == 0) sm.ln = 0;
  __syncthreads();

  // ---- stage window: 364 lines x 8 chunks; chunk c stored at c^(L&7) ----
#pragma unroll
  for (int i = 0; i < 12; ++i) {
    const int t = tid + i * 256;                   // 0..3071, need < 2912
    if (t < NL_ * 8) {
      const int L = t >> 3, c = t & 7;
      const int ry = L / WIN_W, rx = L - ry * WIN_W;
      const float4 v = *(const float4*)(slab + ((((wy0 + ry) * W_ + wx0 + rx) << 7) + (c << 4)));
      *(float4*)(sm.u.stage + (L << 7) + (((c ^ L) & 7) << 4)) = v;
    }
  }

  // ---- params for 64 tile pixels x 9 taps ----
  for (int e = tid; e < 576; e += 256) {
    const int px  = e & 63;
    const int k   = e >> 6;
    const int row = px >> 4, col = px & 15;
    const int ho  = ho0 + row, wo = wo0 + col;
    const int ky = k / 3, kx = k - ky * 3;
    const int och = (g * K_ + k) * 2;
    const size_t ob = ((size_t)(b * (2 * G_ * K_) + och) * HW_) + ho * W_ + wo;
    const float dy = off[ob];
    const float dx = off[ob + HW_];
    const float m  = msk[((size_t)(b * (G_ * K_) + g * K_ + k) * HW_) + ho * W_ + wo];

    const float py  = (float)(ho - 1 + ky) + dy;
    const float pxx = (float)(wo - 1 + kx) + dx;
    const float fy = floorf(py), fx = floorf(pxx);
    const int y0 = (int)fy, x0 = (int)fx;
    const int y1 = y0 + 1,  x1 = x0 + 1;
    const float ly = py - fy, lx = pxx - fx;

    const bool vy0 = ((unsigned)y0 < (unsigned)H_), vy1 = ((unsigned)y1 < (unsigned)H_);
    const bool vx0 = ((unsigned)x0 < (unsigned)W_), vx1 = ((unsigned)x1 < (unsigned)W_);
    const float wy0f = (1.f - ly) * m, wy1f = ly * m;

    float4 w;
    w.x = (vy0 && vx0) ? wy0f * (1.f - lx) : 0.f;
    w.y = (vy0 && vx1) ? wy0f * lx         : 0.f;
    w.z = (vy1 && vx0) ? wy1f * (1.f - lx) : 0.f;
    w.w = (vy1 && vx1) ? wy1f * lx         : 0.f;

    const int y0c = min(max(y0, 0), H_ - 1), y1c = min(max(y1, 0), H_ - 1);
    const int x0c = min(max(x0, 0), W_ - 1), x1c = min(max(x1, 0), W_ - 1);

    const int ry0 = y0c - wy0, ry1 = y1c - wy0;
    const int rx0 = x0c - wx0, rx1 = x1c - wx0;
    const bool inw = ((unsigned)ry0 < WIN_H) & ((unsigned)ry1 < WIN_H) &
                     ((unsigned)rx0 < WIN_W) & ((unsigned)rx1 < WIN_W);

    if (inw) {
      sm.l[e] = make_short4((short)(ry0 * WIN_W + rx0), (short)(ry0 * WIN_W + rx1),
                            (short)(ry1 * WIN_W + rx0), (short)(ry1 * WIN_W + rx1));
      sm.w[e] = w;
    } else {  // rare: queue for post-loop global fallback, zero main weights
      sm.l[e] = make_short4(0, 0, 0, 0);
      sm.w[e] = make_float4(0.f, 0.f, 0.f, 0.f);
      const int idx = atomicAdd(&sm.ln, 1);
      if (idx < 64) {
        sm.l_px[idx] = px;
        sm.l_o[idx]  = make_int4((y0c * W_ + x0c) << 7, (y0c * W_ + x1c) << 7,
                                 (y1c * W_ + x0c) << 7, (y1c * W_ + x1c) << 7);
        sm.l_w[idx]  = w;
      }
    }
  }
  __syncthreads();

  // ---- hot loop: branch-free LDS gathers, 2 pixels x 8 channels/thread ----
  const int ci16 = (tid & 7) << 4;
  const int wi   = tid >> 3;

  float a0[8] = {0.f, 0.f, 0.f, 0.f, 0.f, 0.f, 0.f, 0.f};
  float a1[8] = {0.f, 0.f, 0.f, 0.f, 0.f, 0.f, 0.f, 0.f};

  const char* st = sm.u.stage;
#pragma unroll 3
  for (int k = 0; k < 9; ++k) {
    const int eA = k * 64 + wi;
    const short4 lA = sm.l[eA];
    const float4 wA = sm.w[eA];
    const short4 lB = sm.l[eA + 32];
    const float4 wB = sm.w[eA + 32];

    const float4 rA0 = *(const float4*)(st + ((int)lA.x << 7) + (ci16 ^ ((lA.x & 7) << 4)));
    const float4 rA1 = *(const float4*)(st + ((int)lA.y << 7) + (ci16 ^ ((lA.y & 7) << 4)));
    const float4 rA2 = *(const float4*)(st + ((int)lA.z << 7) + (ci16 ^ ((lA.z & 7) << 4)));
    const float4 rA3 = *(const float4*)(st + ((int)lA.w << 7) + (ci16 ^ ((lA.w & 7) << 4)));
    const float4 rB0 = *(const float4*)(st + ((int)lB.x << 7) + (ci16 ^ ((lB.x & 7) << 4)));
    const float4 rB1 = *(const float4*)(st + ((int)lB.y << 7) + (ci16 ^ ((lB.y & 7) << 4)));
    const float4 rB2 = *(const float4*)(st + ((int)lB.z << 7) + (ci16 ^ ((lB.z & 7) << 4)));
    const float4 rB3 = *(const float4*)(st + ((int)lB.w << 7) + (ci16 ^ ((lB.w & 7) << 4)));

    const __half* hA0 = (const __half*)&rA0;
    const __half* hA1 = (const __half*)&rA1;
    const __half* hA2 = (const __half*)&rA2;
    const __half* hA3 = (const __half*)&rA3;
    const __half* hB0 = (const __half*)&rB0;
    const __half* hB1 = (const __half*)&rB1;
    const __half* hB2 = (const __half*)&rB2;
    const __half* hB3 = (const __half*)&rB3;
#pragma unroll
    for (int j = 0; j < 8; ++j) {
      float s0 = a0[j];
      s0 = fmaf(wA.x, __half2float(hA0[j]), s0);
      s0 = fmaf(wA.y, __half2float(hA1[j]), s0);
      s0 = fmaf(wA.z, __half2float(hA2[j]), s0);
      s0 = fmaf(wA.w, __half2float(hA3[j]), s0);
      a0[j] = s0;
      float s1 = a1[j];
      s1 = fmaf(wB.x, __half2float(hB0[j]), s1);
      s1 = fmaf(wB.y, __half2float(hB1[j]), s1);
      s1 = fmaf(wB.z, __half2float(hB2[j]), s1);
      s1 = fmaf(wB.w, __half2float(hB3[j]), s1);
      a1[j] = s1;
    }
  }

  __syncthreads();  // stage dead; overlay output tile
  {
    const int ci = tid & 7;
#pragma unroll
    for (int j = 0; j < 8; ++j) {
      sm.u.ot[ci * 8 + j][wi]      = a0[j];
      sm.u.ot[ci * 8 + j][wi + 32] = a1[j];
    }
  }
  __syncthreads();

  // ---- fallback list (usually empty): global gather + LDS atomicAdd ----
  const int ln = min(sm.ln, 64);
  for (int i = 0; i < ln; ++i) {
    if (wi == (i & 31)) {  // 8 threads (ci 0..7) per item
      const int ci = tid & 7;
      const int fpx = sm.l_px[i];
      const int4   o = sm.l_o[i];
      const float4 w = sm.l_w[i];
      const float4 v0 = *(const float4*)(slab + (o.x + ci16));
      const float4 v1 = *(const float4*)(slab + (o.y + ci16));
      const float4 v2 = *(const float4*)(slab + (o.z + ci16));
      const float4 v3 = *(const float4*)(slab + (o.w + ci16));
      const __half* h0 = (const __half*)&v0;
      const __half* h1 = (const __half*)&v1;
      const __half* h2 = (const __half*)&v2;
      const __half* h3 = (const __half*)&v3;
#pragma unroll
      for (int j = 0; j < 8; ++j) {
        const float add = w.x * __half2float(h0[j]) + w.y * __half2float(h1[j]) +
                          w.z * __half2float(h2[j]) + w.w * __half2float(h3[j]);
        atomicAdd(&sm.u.ot[ci * 8 + j][fpx], add);
      }
    }
  }
  if (ln) __syncthreads();

  // ---- stores: wave covers 64 px of one channel (4 x 64B segments) ----
  float* obp = out + ((size_t)(b * C_ + g * CG_)) * HW_;
#pragma unroll
  for (int q = 0; q < 16; ++q) {
    const int flat = q * 256 + tid;
    const int c  = flat >> 6;          // uniform across a wave
    const int px = flat & 63;
    const int ho = ho0 + (px >> 4), wo = wo0 + (px & 15);
    obp[(size_t)c * HW_ + ho * W_ + wo] = sm.u.ot[c][px];
  }
}

// ---------------------------------------------------------------------------
// Fallback (no workspace): fp32 NCHW gathers, 4 ch/thread.
// ---------------------------------------------------------------------------
__global__ __launch_bounds__(256) void deform_f32_nchw(const float* __restrict__ x,
                                                       const float* __restrict__ off,
                                                       const float* __restrict__ msk,
                                                       float* __restrict__ out) {
  __shared__ int4   s_o[144];
  __shared__ float4 s_w[144];
  const int woq = blockIdx.x;
  const int ho  = blockIdx.y;
  const int b   = blockIdx.z >> 2;
  const int g   = blockIdx.z & 3;
  const int tid = threadIdx.x;

  if (tid < 144) {
    const int wi = tid / 9, k = tid - wi * 9;
    const int wo = woq * 16 + wi;
    const int ky = k / 3, kx = k - ky * 3;
    const int och = (g * K_ + k) * 2;
    const size_t ob = ((size_t)(b * (2 * G_ * K_) + och) * H_ + ho) * W_ + wo;
    const float dy = off[ob];
    const float dx = off[ob + HW_];
    const float m  = msk[((size_t)(b * (G_ * K_) + g * K_ + k) * H_ + ho) * W_ + wo];
    const float py = (float)(ho - 1 + ky) + dy;
    const float px = (float)(wo - 1 + kx) + dx;
    const float fy = floorf(py), fx = floorf(px);
    const int y0 = (int)fy, x0 = (int)fx;
    const int y1 = y0 + 1,  x1 = x0 + 1;
    const float ly = py - fy, lx = px - fx;
    const bool vy0 = ((unsigned)y0 < (unsigned)H_), vy1 = ((unsigned)y1 < (unsigned)H_);
    const bool vx0 = ((unsigned)x0 < (unsigned)W_), vx1 = ((unsigned)x1 < (unsigned)W_);
    const float wy0 = (1.f - ly) * m, wy1 = ly * m;
    float4 w;
    w.x = (vy0 && vx0) ? wy0 * (1.f - lx) : 0.f;
    w.y = (vy0 && vx1) ? wy0 * lx         : 0.f;
    w.z = (vy1 && vx0) ? wy1 * (1.f - lx) : 0.f;
    w.w = (vy1 && vx1) ? wy1 * lx         : 0.f;
    const int y0c = min(max(y0, 0), H_ - 1), y1c = min(max(y1, 0), H_ - 1);
    const int x0c = min(max(x0, 0), W_ - 1), x1c = min(max(x1, 0), W_ - 1);
    s_o[tid] = make_int4(y0c * W_ + x0c, y0c * W_ + x1c, y1c * W_ + x0c, y1c * W_ + x1c);
    s_w[tid] = w;
  }
  __syncthreads();

  const int ci = tid & 15, wi = tid >> 4;
  const float* xb = x + (size_t)(b * C_ + g * CG_ + ci * 4) * HW_;
  float a0 = 0.f, a1 = 0.f, a2 = 0.f, a3 = 0.f;
#pragma unroll
  for (int k = 0; k < 9; ++k) {
    const int e = wi * 9 + k;
    const int4   o = s_o[e];
    const float4 w = s_w[e];
    a0 += w.x * xb[o.x] + w.y * xb[o.y] + w.z * xb[o.z] + w.w * xb[o.w];
    const float* x1p = xb + HW_;
    a1 += w.x * x1p[o.x] + w.y * x1p[o.y] + w.z * x1p[o.z] + w.w * x1p[o.w];
    const float* x2p = xb + 2 * HW_;
    a2 += w.x * x2p[o.x] + w.y * x2p[o.y] + w.z * x2p[o.z] + w.w * x2p[o.w];
    const float* x3p = xb + 3 * HW_;
    a3 += w.x * x3p[o.x] + w.y * x3p[o.y] + w.z * x3p[o.z] + w.w * x3p[o.w];
  }
  float* ob = out + ((size_t)(b * C_ + g * CG_ + ci * 4)) * HW_ + ho * W_ + woq * 16 + wi;
  ob[0] = a0; ob[HW_] = a1; ob[2 * HW_] = a2; ob[3 * HW_] = a3;
}

// ---------------------------------------------------------------------------
extern "C" void kernel_launch(void* const* d_in, const int* in_sizes, int n_in,
                              void* d_out, int out_size, void* d_ws, size_t ws_size,
                              hipStream_t stream) {
  const float* inp = (const float*)d_in[0];
  const float* off = (const float*)d_in[1];
  const float* msk = (const float*)d_in[2];
  float* out = (float*)d_out;

  const size_t need = (size_t)B_ * C_ * HW_ * sizeof(__half);  // 16.8 MB
  if (ws_size >= need) {
    __half* xt = (__half*)d_ws;
    to_ghwc_f16<<<dim3(HW_ / 64, G_, B_), 256, 0, stream>>>(inp, xt);
    deform_g16s<<<dim3(H_ * B_ * G_), 256, 0, stream>>>(xt, off, msk, out);
  } else {
    deform_f32_nchw<<<dim3(4, H_, B_ * G_), 256, 0, stream>>>(inp, off, msk, out);
  }
}

// Round 9
// 38.774 us; speedup vs baseline: 8.3537x; 1.2762x over previous
//
#include <hip/hip_runtime.h>
#include <hip/hip_fp16.h>

#define B_  8
#define C_  256
#define H_  64
#define W_  64
#define G_  4
#define CG_ 64
#define K_  9
#define HW_ (H_ * W_)  // 4096

// ---------------------------------------------------------------------------
// Kernel 1: NCHW fp32 -> group-major NHWC fp16  [B,C,HW] -> [B,G,HW,CG]
// ---------------------------------------------------------------------------
__global__ __launch_bounds__(256) void to_ghwc_f16(const float* __restrict__ in,
                                                   __half* __restrict__ out) {
  __shared__ unsigned int tile[32][65];  // [channel-pair][pixel]
  const int b  = blockIdx.z;
  const int p0 = blockIdx.x * 64;
  const int g  = blockIdx.y;
  const int tid = threadIdx.x;
  const float* src = in + (size_t)b * C_ * HW_ + (size_t)g * CG_ * HW_;
  __half* dst = out + ((size_t)(b * G_ + g) * HW_) * CG_;

  const int px  = tid & 63;
  const int cp0 = tid >> 6;
#pragma unroll
  for (int i = 0; i < 8; ++i) {
    const int cp = cp0 + i * 4;
    const int c  = cp * 2;
    const float v0 = src[(size_t)c * HW_ + p0 + px];
    const float v1 = src[(size_t)(c + 1) * HW_ + p0 + px];
    const unsigned int lo = (unsigned int)__half_as_ushort(__float2half(v0));
    const unsigned int hi = (unsigned int)__half_as_ushort(__float2half(v1));
    tile[cp][px] = lo | (hi << 16);
  }
  __syncthreads();

  const int cpair = tid & 31;
  const int pr0   = tid >> 5;
#pragma unroll
  for (int i = 0; i < 8; ++i) {
    const int p = pr0 + i * 8;
    *(unsigned int*)(dst + (size_t)(p0 + p) * CG_ + 2 * cpair) = tile[cpair][p];
  }
}

// ---------------------------------------------------------------------------
// Kernel 2: deformable sampling from [B,G,HW,CG] fp16 (global gathers).
//   4x16 output tile per block; XCD swizzle (bg-major per XCD) keeps the
//   2 MB group slab L2-resident -> FETCH ~= compulsory (verified r6: 15 MB).
//   256 threads = 8 channel-octets x 32 slots; 2 pixels/slot.
//   Hot loop TAP-PAIR BATCHED: issue 16 independent 16B gathers (taps k,k+1)
//   before consuming tap k -> compiler emits vmcnt(8) waits and k+1's loads
//   remain in flight under k's 128 FMAs. This is the MLP the 36-VGPR r6
//   build lacked. launch_bounds(256,3): VGPR cap 168, no spills.
// ---------------------------------------------------------------------------
union DeformSM {
  struct { int4 o[576]; float4 w[576]; } p;  // 18432 B
  float ot[64][65];                          // 16640 B
};

__global__ __launch_bounds__(256, 3) void deform_g16(const __half* __restrict__ x,
                                                     const float* __restrict__ off,
                                                     const float* __restrict__ msk,
                                                     float* __restrict__ out) {
  __shared__ DeformSM sm;

  // XCD-aware swizzle: grid 2048 % 8 == 0; XCD i owns contiguous bg slabs.
  const int orig = blockIdx.x;                    // 0..2047
  const int wgid = (orig & 7) * 256 + (orig >> 3);
  const int tile = wgid & 63;                     // 64 tiles per (b,g)
  const int bg   = wgid >> 6;
  const int ho0  = (tile >> 2) * 4;               // 16 row-tiles
  const int wo0  = (tile & 3) * 16;               // 4 col-tiles
  const int b    = bg >> 2;
  const int g    = bg & 3;
  const int tid  = threadIdx.x;

  // ---- phase 1: params for 64 tile pixels x 9 taps ----
  for (int e = tid; e < 576; e += 256) {
    const int px  = e & 63;           // local pixel id: row*16+col
    const int k   = e >> 6;
    const int row = px >> 4, col = px & 15;
    const int ho  = ho0 + row, wo = wo0 + col;
    const int ky = k / 3, kx = k - ky * 3;
    const int och = (g * K_ + k) * 2;
    const size_t ob = ((size_t)(b * (2 * G_ * K_) + och) * HW_) + ho * W_ + wo;
    const float dy = off[ob];
    const float dx = off[ob + HW_];
    const float m  = msk[((size_t)(b * (G_ * K_) + g * K_ + k) * HW_) + ho * W_ + wo];

    const float py  = (float)(ho - 1 + ky) + dy;
    const float pxx = (float)(wo - 1 + kx) + dx;
    const float fy = floorf(py), fx = floorf(pxx);
    const int y0 = (int)fy, x0 = (int)fx;
    const int y1 = y0 + 1,  x1 = x0 + 1;
    const float ly = py - fy, lx = pxx - fx;

    const bool vy0 = ((unsigned)y0 < (unsigned)H_), vy1 = ((unsigned)y1 < (unsigned)H_);
    const bool vx0 = ((unsigned)x0 < (unsigned)W_), vx1 = ((unsigned)x1 < (unsigned)W_);
    const float wy0 = (1.f - ly) * m, wy1 = ly * m;

    float4 w;
    w.x = (vy0 && vx0) ? wy0 * (1.f - lx) : 0.f;
    w.y = (vy0 && vx1) ? wy0 * lx         : 0.f;
    w.z = (vy1 && vx0) ? wy1 * (1.f - lx) : 0.f;
    w.w = (vy1 && vx1) ? wy1 * lx         : 0.f;

    const int y0c = min(max(y0, 0), H_ - 1), y1c = min(max(y1, 0), H_ - 1);
    const int x0c = min(max(x0, 0), W_ - 1), x1c = min(max(x1, 0), W_ - 1);

    int4 o;  // BYTE offsets into group slab (pix * CG * 2 = pix << 7)
    o.x = (y0c * W_ + x0c) << 7;
    o.y = (y0c * W_ + x1c) << 7;
    o.z = (y1c * W_ + x0c) << 7;
    o.w = (y1c * W_ + x1c) << 7;
    sm.p.o[e] = o;
    sm.p.w[e] = w;
  }
  __syncthreads();

  // ---- phase 2: 2 tile-pixels x 8 channels per thread, tap-pair batched ----
  const int ci16 = (tid & 7) * 16;   // byte offset of channel octet
  const int wi   = tid >> 3;         // slot 0..31
  const char* base = (const char*)x + (size_t)(b * G_ + g) * (HW_ * CG_ * 2);

  float a0[8] = {0.f, 0.f, 0.f, 0.f, 0.f, 0.f, 0.f, 0.f};
  float a1[8] = {0.f, 0.f, 0.f, 0.f, 0.f, 0.f, 0.f, 0.f};

#pragma unroll
  for (int kp = 0; kp < 5; ++kp) {
    const int e0 = (2 * kp) * 64 + wi;

    // --- issue tap k0's 8 loads ---
    const int4   oA0 = sm.p.o[e0];
    const float4 wA0 = sm.p.w[e0];
    const int4   oB0 = sm.p.o[e0 + 32];
    const float4 wB0 = sm.p.w[e0 + 32];
    const float4 rA00 = *(const float4*)(base + (oA0.x + ci16));
    const float4 rA01 = *(const float4*)(base + (oA0.y + ci16));
    const float4 rA02 = *(const float4*)(base + (oA0.z + ci16));
    const float4 rA03 = *(const float4*)(base + (oA0.w + ci16));
    const float4 rB00 = *(const float4*)(base + (oB0.x + ci16));
    const float4 rB01 = *(const float4*)(base + (oB0.y + ci16));
    const float4 rB02 = *(const float4*)(base + (oB0.z + ci16));
    const float4 rB03 = *(const float4*)(base + (oB0.w + ci16));

    // --- issue tap k1's 8 loads before consuming k0 (static branch) ---
    float4 rA10, rA11, rA12, rA13, rB10, rB11, rB12, rB13;
    float4 wA1, wB1;
    if (kp < 4) {
      const int e1 = e0 + 64;
      const int4 oA1 = sm.p.o[e1];
      wA1 = sm.p.w[e1];
      const int4 oB1 = sm.p.o[e1 + 32];
      wB1 = sm.p.w[e1 + 32];
      rA10 = *(const float4*)(base + (oA1.x + ci16));
      rA11 = *(const float4*)(base + (oA1.y + ci16));
      rA12 = *(const float4*)(base + (oA1.z + ci16));
      rA13 = *(const float4*)(base + (oA1.w + ci16));
      rB10 = *(const float4*)(base + (oB1.x + ci16));
      rB11 = *(const float4*)(base + (oB1.y + ci16));
      rB12 = *(const float4*)(base + (oB1.z + ci16));
      rB13 = *(const float4*)(base + (oB1.w + ci16));
    }

    // --- consume tap k0 ---
    {
      const __half* h0 = (const __half*)&rA00;
      const __half* h1 = (const __half*)&rA01;
      const __half* h2 = (const __half*)&rA02;
      const __half* h3 = (const __half*)&rA03;
      const __half* q0 = (const __half*)&rB00;
      const __half* q1 = (const __half*)&rB01;
      const __half* q2 = (const __half*)&rB02;
      const __half* q3 = (const __half*)&rB03;
#pragma unroll
      for (int j = 0; j < 8; ++j) {
        float s0 = a0[j];
        s0 = fmaf(wA0.x, __half2float(h0[j]), s0);
        s0 = fmaf(wA0.y, __half2float(h1[j]), s0);
        s0 = fmaf(wA0.z, __half2float(h2[j]), s0);
        s0 = fmaf(wA0.w, __half2float(h3[j]), s0);
        a0[j] = s0;
        float s1 = a1[j];
        s1 = fmaf(wB0.x, __half2float(q0[j]), s1);
        s1 = fmaf(wB0.y, __half2float(q1[j]), s1);
        s1 = fmaf(wB0.z, __half2float(q2[j]), s1);
        s1 = fmaf(wB0.w, __half2float(q3[j]), s1);
        a1[j] = s1;
      }
    }

    // --- consume tap k1 ---
    if (kp < 4) {
      const __half* h0 = (const __half*)&rA10;
      const __half* h1 = (const __half*)&rA11;
      const __half* h2 = (const __half*)&rA12;
      const __half* h3 = (const __half*)&rA13;
      const __half* q0 = (const __half*)&rB10;
      const __half* q1 = (const __half*)&rB11;
      const __half* q2 = (const __half*)&rB12;
      const __half* q3 = (const __half*)&rB13;
#pragma unroll
      for (int j = 0; j < 8; ++j) {
        float s0 = a0[j];
        s0 = fmaf(wA1.x, __half2float(h0[j]), s0);
        s0 = fmaf(wA1.y, __half2float(h1[j]), s0);
        s0 = fmaf(wA1.z, __half2float(h2[j]), s0);
        s0 = fmaf(wA1.w, __half2float(h3[j]), s0);
        a0[j] = s0;
        float s1 = a1[j];
        s1 = fmaf(wB1.x, __half2float(q0[j]), s1);
        s1 = fmaf(wB1.y, __half2float(q1[j]), s1);
        s1 = fmaf(wB1.z, __half2float(q2[j]), s1);
        s1 = fmaf(wB1.w, __half2float(q3[j]), s1);
        a1[j] = s1;
      }
    }
  }

  __syncthreads();  // params dead; reuse LDS as staging tile
  {
    const int ci = tid & 7;
#pragma unroll
    for (int j = 0; j < 8; ++j) {
      sm.ot[ci * 8 + j][wi]      = a0[j];
      sm.ot[ci * 8 + j][wi + 32] = a1[j];
    }
  }
  __syncthreads();

  // ---- phase 3: stores; wave covers 64 px of one channel = 4 x 64B segs ----
  float* ob = out + ((size_t)(b * C_ + g * CG_)) * HW_;
#pragma unroll
  for (int q = 0; q < 16; ++q) {
    const int flat = q * 256 + tid;
    const int c  = flat >> 6;          // uniform across a wave
    const int px = flat & 63;
    const int ho = ho0 + (px >> 4), wo = wo0 + (px & 15);
    ob[(size_t)c * HW_ + ho * W_ + wo] = sm.ot[c][px];
  }
}

// ---------------------------------------------------------------------------
// Fallback (no workspace): fp32 NCHW gathers, 4 ch/thread.
// ---------------------------------------------------------------------------
__global__ __launch_bounds__(256) void deform_f32_nchw(const float* __restrict__ x,
                                                       const float* __restrict__ off,
                                                       const float* __restrict__ msk,
                                                       float* __restrict__ out) {
  __shared__ int4   s_o[144];
  __shared__ float4 s_w[144];
  const int woq = blockIdx.x;
  const int ho  = blockIdx.y;
  const int b   = blockIdx.z >> 2;
  const int g   = blockIdx.z & 3;
  const int tid = threadIdx.x;

  if (tid < 144) {
    const int wi = tid / 9, k = tid - wi * 9;
    const int wo = woq * 16 + wi;
    const int ky = k / 3, kx = k - ky * 3;
    const int och = (g * K_ + k) * 2;
    const size_t ob = ((size_t)(b * (2 * G_ * K_) + och) * H_ + ho) * W_ + wo;
    const float dy = off[ob];
    const float dx = off[ob + HW_];
    const float m  = msk[((size_t)(b * (G_ * K_) + g * K_ + k) * H_ + ho) * W_ + wo];
    const float py = (float)(ho - 1 + ky) + dy;
    const float px = (float)(wo - 1 + kx) + dx;
    const float fy = floorf(py), fx = floorf(px);
    const int y0 = (int)fy, x0 = (int)fx;
    const int y1 = y0 + 1,  x1 = x0 + 1;
    const float ly = py - fy, lx = px - fx;
    const bool vy0 = ((unsigned)y0 < (unsigned)H_), vy1 = ((unsigned)y1 < (unsigned)H_);
    const bool vx0 = ((unsigned)x0 < (unsigned)W_), vx1 = ((unsigned)x1 < (unsigned)W_);
    const float wy0 = (1.f - ly) * m, wy1 = ly * m;
    float4 w;
    w.x = (vy0 && vx0) ? wy0 * (1.f - lx) : 0.f;
    w.y = (vy0 && vx1) ? wy0 * lx         : 0.f;
    w.z = (vy1 && vx0) ? wy1 * (1.f - lx) : 0.f;
    w.w = (vy1 && vx1) ? wy1 * lx         : 0.f;
    const int y0c = min(max(y0, 0), H_ - 1), y1c = min(max(y1, 0), H_ - 1);
    const int x0c = min(max(x0, 0), W_ - 1), x1c = min(max(x1, 0), W_ - 1);
    s_o[tid] = make_int4(y0c * W_ + x0c, y0c * W_ + x1c, y1c * W_ + x0c, y1c * W_ + x1c);
    s_w[tid] = w;
  }
  __syncthreads();

  const int ci = tid & 15, wi = tid >> 4;
  const float* xb = x + (size_t)(b * C_ + g * CG_ + ci * 4) * HW_;
  float a0 = 0.f, a1 = 0.f, a2 = 0.f, a3 = 0.f;
#pragma unroll
  for (int k = 0; k < 9; ++k) {
    const int e = wi * 9 + k;
    const int4   o = s_o[e];
    const float4 w = s_w[e];
    a0 += w.x * xb[o.x] + w.y * xb[o.y] + w.z * xb[o.z] + w.w * xb[o.w];
    const float* x1p = xb + HW_;
    a1 += w.x * x1p[o.x] + w.y * x1p[o.y] + w.z * x1p[o.z] + w.w * x1p[o.w];
    const float* x2p = xb + 2 * HW_;
    a2 += w.x * x2p[o.x] + w.y * x2p[o.y] + w.z * x2p[o.z] + w.w * x2p[o.w];
    const float* x3p = xb + 3 * HW_;
    a3 += w.x * x3p[o.x] + w.y * x3p[o.y] + w.z * x3p[o.z] + w.w * x3p[o.w];
  }
  float* ob = out + ((size_t)(b * C_ + g * CG_ + ci * 4)) * HW_ + ho * W_ + woq * 16 + wi;
  ob[0] = a0; ob[HW_] = a1; ob[2 * HW_] = a2; ob[3 * HW_] = a3;
}

// ---------------------------------------------------------------------------
extern "C" void kernel_launch(void* const* d_in, const int* in_sizes, int n_in,
                              void* d_out, int out_size, void* d_ws, size_t ws_size,
                              hipStream_t stream) {
  const float* inp = (const float*)d_in[0];
  const float* off = (const float*)d_in[1];
  const float* msk = (const float*)d_in[2];
  float* out = (float*)d_out;

  const size_t need = (size_t)B_ * C_ * HW_ * sizeof(__half);  // 16.8 MB
  if (ws_size >= need) {
    __half* xt = (__half*)d_ws;
    to_ghwc_f16<<<dim3(HW_ / 64, G_, B_), 256, 0, stream>>>(inp, xt);
    deform_g16<<<dim3(H_ * B_ * G_), 256, 0, stream>>>(xt, off, msk, out);
  } else {
    deform_f32_nchw<<<dim3(4, H_, B_ * G_), 256, 0, stream>>>(inp, off, msk, out);
  }
}